// Round 19
// baseline (892.033 us; speedup 1.0000x reference)
//
#include <hip/hip_runtime.h>
#include <hip/hip_bf16.h>

#define NN 4096
#define IC 128
#define OC 128
#define ED 16
#define EPB 64
#define NT 256
#define NSLOT 16
#define NBLK 512
#define NCPY 8

typedef __bf16 bf16x8 __attribute__((ext_vector_type(8)));
typedef float  f32x16 __attribute__((ext_vector_type(16)));

// raw barrier: drain LDS ops only; global loads/atomics stay in flight
#define BAR() do { asm volatile("s_waitcnt lgkmcnt(0)" ::: "memory"); \
    __builtin_amdgcn_s_barrier(); \
    __builtin_amdgcn_sched_barrier(0); } while (0)

__device__ __forceinline__ unsigned short bf16u(float f) {   // RNE f32->bf16
    unsigned int u = __float_as_uint(f);
    u = (u + 0x7FFFu + ((u >> 16) & 1u)) >> 16;
    return (unsigned short)u;
}
__device__ __forceinline__ float bf16tof(unsigned short h) {
    return __uint_as_float(((unsigned int)h) << 16);
}
__device__ __forceinline__ int swzk(int row) { return (row ^ (row >> 3)) & 7; }

// ---- Phase 1: xw1b = x@W1[:128]+b1; zero out; fused 8-replica hist ------
__global__ __launch_bounds__(128) void k_xw1(
    const float* __restrict__ x, const float* __restrict__ W1,
    const float* __restrict__ b1, const int* __restrict__ eidx,
    float* __restrict__ xw1b, float* __restrict__ out,
    int* __restrict__ hist8, int E)
{
    __shared__ float xs[8][IC];
    const int t = threadIdx.x;
    const int r0 = blockIdx.x * 8;
    #pragma unroll
    for (int r = 0; r < 8; ++r) xs[r][t] = x[(size_t)(r0 + r) * IC + t];

    const float4 z = make_float4(0.f, 0.f, 0.f, 0.f);
    float4* o4 = (float4*)out;
    o4[blockIdx.x * 256 + t]       = z;
    o4[blockIdx.x * 256 + 128 + t] = z;

    {   // fused hist; copy mapping matches k_scatter: edge e -> (e>>8)&7
        const int e0 = blockIdx.x * 512;
        #pragma unroll
        for (int j = 0; j < 4; ++j) {
            const int k = (2 * blockIdx.x + (j >> 1)) & (NCPY - 1);
            atomicAdd(&hist8[k * 4096 + eidx[E + e0 + t + j * 128]], 1);
        }
    }

    __syncthreads();
    float acc[8];
    const float bb = b1[t];
    #pragma unroll
    for (int r = 0; r < 8; ++r) acc[r] = bb;
    #pragma unroll 4
    for (int k = 0; k < IC; ++k) {
        const float w = W1[(size_t)k * OC + t];
        #pragma unroll
        for (int r = 0; r < 8; ++r) acc[r] = fmaf(xs[r][k], w, acc[r]);
    }
    #pragma unroll
    for (int r = 0; r < 8; ++r) xw1b[(size_t)(r0 + r) * OC + t] = acc[r];
}

// -------- scan (16-block A/B) + scatter (8-replica) -----------------------
__global__ __launch_bounds__(256) void k_scanA(
    const int* __restrict__ hist8, int* __restrict__ binloc,
    int* __restrict__ blocksum)
{
    __shared__ int sb[256];
    const int t = threadIdx.x;
    const int bin = blockIdx.x * 256 + t;
    int s = 0;
    #pragma unroll
    for (int k = 0; k < NCPY; ++k) s += hist8[k * 4096 + bin];
    sb[t] = s;
    __syncthreads();
    if (t == 0) {
        int a = 0;
        for (int i = 0; i < 256; ++i) { const int v = sb[i]; sb[i] = a; a += v; }
        blocksum[blockIdx.x] = a;
    }
    __syncthreads();
    binloc[bin] = sb[t];
}

__global__ __launch_bounds__(256) void k_scanB(
    const int* __restrict__ hist8, const int* __restrict__ binloc,
    const int* __restrict__ blocksum, int* __restrict__ cursor8,
    int* __restrict__ colstart, int E)
{
    __shared__ int baseL;
    const int t = threadIdx.x;
    if (t == 0) {
        int a = 0;
        for (int j = 0; j < (int)blockIdx.x; ++j) a += blocksum[j];
        baseL = a;
    }
    __syncthreads();
    const int bin = blockIdx.x * 256 + t;
    int off = baseL + binloc[bin];
    colstart[bin] = off;
    #pragma unroll
    for (int k = 0; k < NCPY; ++k) {
        cursor8[k * 4096 + bin] = off;
        off += hist8[k * 4096 + bin];
    }
    if (bin == 4095) colstart[4096] = E;
}

__global__ void k_scatter(const int* __restrict__ eidx, int* __restrict__ cursor8,
                          int2* __restrict__ csr, int E) {
    const int i = blockIdx.x * blockDim.x + threadIdx.x;
    const int k = blockIdx.x & (NCPY - 1);
    if (i < E) {
        const int row = eidx[i];
        const int col = eidx[E + i];
        const int pos = atomicAdd(&cursor8[k * 4096 + col], 1);
        csr[pos] = make_int2(row, col);
    }
}

// ---------------- Phase 2: R17 kernel + reps loop (profiling probe) ------
// reps=1 -> byte-identical behavior to round 17 (best: 136.9us).
// The probe dispatch (reps=10, scratch out) runs ~810us so it EXCEEDS the
// ~650us harness poison fills and surfaces in rocprof top-5 WITH counters
// (MfmaUtil/VALUBusy/FETCH/LDS_BANK_CONFLICT) -- first-ever counter read
// on the hot kernel.
__global__ __launch_bounds__(NT, 2) void k_edge10(
    const int2* __restrict__ csr, const float* __restrict__ eattr,
    const float* __restrict__ xw1b, const float* __restrict__ W1,
    const float* __restrict__ W2, const float* __restrict__ b2,
    const int* __restrict__ colstart, float* __restrict__ out, int E,
    int reps)
{
    extern __shared__ char smem[];
    char*   const h1hi = smem;                      // 16KB bf16 [64e][128k] swz
    char*   const h1lo = smem + 16384;              // 16KB
    float4* const eaL  = (float4*)(smem + 32768);   // [2][256] swz (8KB)
    float4* const w1L  = (float4*)(smem + 40960);   // [512] (8KB)
    float*  const lacc = (float*)(smem + 49152);    // [16][128] (8KB)
    int*    const srowL = (int*)(smem + 57344);     // [4][64]
    int*    const scolL = srowL + 256;              // [4][64]

    const int t   = threadIdx.x;
    const int l   = t & 63;
    const int wid = t >> 6;                 // 4 waves
    const int cg  = t & 15, eg = t >> 4;    // layer-1 tile: 4e x 8c; eg 0..15
    const int c0  = cg << 3, e0 = eg << 2;
    const int sz  = (eg >> 1) & 3;          // per-edge swizzle key ((e>>3)&3)
    const int em  = t >> 2, q = t & 3;      // ea gather: 4 threads/edge
    const int esz = (em >> 3) & 3;

    const int lm  = l & 31;
    const int hi  = l >> 5;
    const int c2  = wid * 32 + lm;          // this lane's output channel

    w1L[t]       = ((const float4*)(W1 + (size_t)IC * OC))[t];
    w1L[t + NT]  = ((const float4*)(W1 + (size_t)IC * OC))[t + NT];

    // W2 -> register hi/lo fragments (batch-invariant, 64 VGPR)
    bf16x8 w2h[8], w2l[8];
    #pragma unroll
    for (int s = 0; s < 8; ++s) {
        union { unsigned short us[8]; bf16x8 v; } Uh, Ul;
        #pragma unroll
        for (int j = 0; j < 8; ++j) {
            const float w = W2[(size_t)(s * 16 + hi * 8 + j) * OC + c2];
            const unsigned short h = bf16u(w);
            Uh.us[j] = h;
            Ul.us[j] = bf16u(w - bf16tof(h));
        }
        w2h[s] = Uh.v; w2l[s] = Ul.v;
    }
    const float b2s = b2[c2];

    const int nper = (E / EPB) / NBLK;      // 8 batches per block
    const int ibb  = blockIdx.x * nper;

    for (int rep = 0; rep < reps; ++rep) {
        __syncthreads();                    // prev rep's flush reads done

        #pragma unroll
        for (int i = 0; i < NSLOT * OC / NT; ++i) lacc[t + NT * i] = 0.f;

        // ---- prologue: idx(0),idx(1) -> LDS; ea(0) -> eaL[0]; xw -> regs ----
        if (t < EPB) {
            const int2 r0v = csr[(size_t)ibb * EPB + t];
            srowL[t] = r0v.x; scolL[t] = r0v.y;
            const int ib1 = (nper > 1) ? 1 : 0;
            const int2 r1v = csr[(size_t)(ibb + ib1) * EPB + t];
            srowL[64 + t] = r1v.x; scolL[64 + t] = r1v.y;
        }
        __syncthreads();
        const int colbase0 = scolL[0];      // block-fixed lacc anchor

        float4 pA;
        {
            const int r = srowL[em], c = scolL[em];
            pA = ((const float4*)(eattr + ((size_t)r * NN + c) * ED))[q];
        }
        eaL[(em * 4 + q) ^ esz] = pA;
        float4 xa[4], xb[4];
        #pragma unroll
        for (int ri = 0; ri < 4; ++ri) {
            const int row = srowL[e0 + ri];
            const float4* p = (const float4*)(xw1b + (size_t)row * OC + c0);
            xa[ri] = p[0]; xb[ri] = p[1];
        }
        int2 pidx;
        {
            const int ib2 = (nper > 2) ? 2 : (nper - 1);
            pidx = (t < EPB) ? csr[(size_t)(ibb + ib2) * EPB + t] : make_int2(0, 0);
        }
        __syncthreads();                    // eaL[0] visible

        for (int ii = 0; ii < nper; ++ii) {
            const int cb  = ii & 1;         // ea buffer of batch ii
            const int ib4 = ii & 3;         // idx buffer of batch ii

            // ==== Phase A: layer-1 + staging writes + prefetch issue =====
            float4 ha[4], hb[4];
            #pragma unroll
            for (int ri = 0; ri < 4; ++ri) { ha[ri] = xa[ri]; hb[ri] = xb[ri]; }
            #pragma unroll
            for (int dc = 0; dc < 4; ++dc) {
                float4 ev[4];
                #pragma unroll
                for (int ri = 0; ri < 4; ++ri)
                    ev[ri] = eaL[cb * 256 + ((((e0 + ri) * 4 + dc)) ^ sz)];
                #pragma unroll
                for (int dd = 0; dd < 4; ++dd) {
                    const int d = dc * 4 + dd;
                    const float4 wA = w1L[d * 32 + cg * 2];
                    const float4 wB = w1L[d * 32 + cg * 2 + 1];
                    #pragma unroll
                    for (int ri = 0; ri < 4; ++ri) {
                        const float evd = (dd == 0) ? ev[ri].x : (dd == 1) ? ev[ri].y
                                         : (dd == 2) ? ev[ri].z : ev[ri].w;
                        ha[ri].x = fmaf(evd, wA.x, ha[ri].x);
                        ha[ri].y = fmaf(evd, wA.y, ha[ri].y);
                        ha[ri].z = fmaf(evd, wA.z, ha[ri].z);
                        ha[ri].w = fmaf(evd, wA.w, ha[ri].w);
                        hb[ri].x = fmaf(evd, wB.x, hb[ri].x);
                        hb[ri].y = fmaf(evd, wB.y, hb[ri].y);
                        hb[ri].z = fmaf(evd, wB.z, hb[ri].z);
                        hb[ri].w = fmaf(evd, wB.w, hb[ri].w);
                    }
                }
            }
            #pragma unroll
            for (int ri = 0; ri < 4; ++ri) {
                const int row = e0 + ri;
                float v[8] = { ha[ri].x, ha[ri].y, ha[ri].z, ha[ri].w,
                               hb[ri].x, hb[ri].y, hb[ri].z, hb[ri].w };
                union { unsigned short us[8]; uint4 qv; } Hh, Hl;
                #pragma unroll
                for (int j = 0; j < 8; ++j) {
                    const float f = fmaxf(v[j], 0.f);
                    const unsigned short h = bf16u(f);
                    Hh.us[j] = h;
                    Hl.us[j] = bf16u(f - bf16tof(h));
                }
                const int boff = (cg * 16) ^ (swzk(row) << 4);
                *(uint4*)(h1hi + row * 256 + boff) = Hh.qv;
                *(uint4*)(h1lo + row * 256 + boff) = Hl.qv;
            }
            if (t < EPB) {
                srowL[((ii + 2) & 3) * 64 + t] = pidx.x;
                scolL[((ii + 2) & 3) * 64 + t] = pidx.y;
            }
            {
                const int jn = (ii + 1) & 3;
                const int r = srowL[jn * 64 + em], c = scolL[jn * 64 + em];
                pA = ((const float4*)(eattr + ((size_t)r * NN + c) * ED))[q];
                #pragma unroll
                for (int ri = 0; ri < 4; ++ri) {
                    const int row = srowL[jn * 64 + e0 + ri];
                    const float4* p = (const float4*)(xw1b + (size_t)row * OC + c0);
                    xa[ri] = p[0]; xb[ri] = p[1];
                }
            }
            {
                const int iin = (ii + 3 < nper) ? (ii + 3) : (nper - 1);
                pidx = (t < EPB) ? csr[(size_t)(ibb + iin) * EPB + t] : make_int2(0, 0);
            }
            BAR();  // h1 + idx(ii+2) visible; prefetches stay in flight

            // ==== Phase B: layer-2 MFMA + epilogue + eaL(ii+1) write =====
            f32x16 acc0 = (f32x16)(0.0f);
            f32x16 acc1 = (f32x16)(0.0f);
            const int arow0 = lm;
            const int arow1 = 32 + lm;
            const int ak0 = swzk(arow0) << 4;
            const int ak1 = swzk(arow1) << 4;
            #pragma unroll
            for (int s = 0; s < 8; ++s) {
                const int kb = s * 32 + hi * 16;
                const bf16x8 aH0 = *(const bf16x8*)(h1hi + arow0 * 256 + (kb ^ ak0));
                const bf16x8 aL0 = *(const bf16x8*)(h1lo + arow0 * 256 + (kb ^ ak0));
                const bf16x8 aH1 = *(const bf16x8*)(h1hi + arow1 * 256 + (kb ^ ak1));
                const bf16x8 aL1 = *(const bf16x8*)(h1lo + arow1 * 256 + (kb ^ ak1));
                acc0 = __builtin_amdgcn_mfma_f32_32x32x16_bf16(aH0, w2h[s], acc0, 0, 0, 0);
                acc1 = __builtin_amdgcn_mfma_f32_32x32x16_bf16(aH1, w2h[s], acc1, 0, 0, 0);
                acc0 = __builtin_amdgcn_mfma_f32_32x32x16_bf16(aL0, w2h[s], acc0, 0, 0, 0);
                acc1 = __builtin_amdgcn_mfma_f32_32x32x16_bf16(aL1, w2h[s], acc1, 0, 0, 0);
                acc0 = __builtin_amdgcn_mfma_f32_32x32x16_bf16(aH0, w2l[s], acc0, 0, 0, 0);
                acc1 = __builtin_amdgcn_mfma_f32_32x32x16_bf16(aH1, w2l[s], acc1, 0, 0, 0);
            }

            // epilogue: run-combine into persistent lacc
            #pragma unroll
            for (int p = 0; p < 2; ++p) {
                const int mbase = p * 32 + 4 * hi;
                #pragma unroll
                for (int g = 0; g < 4; ++g) {
                    const int eb = mbase + 8 * g;
                    float sv;
                    {
                        const float a0 = (p == 0) ? acc0[4 * g] : acc1[4 * g];
                        sv = fmaxf(a0 + b2s, 0.f);
                    }
                    int ccur = scolL[ib4 * 64 + eb];
                    #pragma unroll
                    for (int j = 1; j < 4; ++j) {
                        const float aj = (p == 0) ? acc0[4 * g + j] : acc1[4 * g + j];
                        const float v = fmaxf(aj + b2s, 0.f);
                        const int c = scolL[ib4 * 64 + eb + j];
                        if (c == ccur) {
                            sv += v;
                        } else {
                            const int slot = ccur - colbase0;
                            if (slot < NSLOT) {
                                if (sv != 0.f) atomicAdd(&lacc[slot * OC + c2], sv);
                            } else {
                                if (sv != 0.f) atomicAdd(&out[(size_t)ccur * OC + c2], sv);
                            }
                            ccur = c; sv = v;
                        }
                    }
                    const int slot = ccur - colbase0;
                    if (slot < NSLOT) {
                        if (sv != 0.f) atomicAdd(&lacc[slot * OC + c2], sv);
                    } else {
                        if (sv != 0.f) atomicAdd(&out[(size_t)ccur * OC + c2], sv);
                    }
                }
            }
            // eaL(ii+1) <- prefetched regs
            eaL[(cb ^ 1) * 256 + ((em * 4 + q) ^ esz)] = pA;
            BAR();  // lacc(batch) complete + eaL(ii+1) visible; h1 reusable
        }

        // ==== single block-end flush ====================================
        const int blk_e0 = ibb * EPB;
        const int blk_e1 = blk_e0 + nper * EPB;
        #pragma unroll 1
        for (int s = 0; s < NSLOT; ++s) {
            const int c = colbase0 + s;
            if (c >= NN) break;
            const int cs = colstart[c];
            const int ce = colstart[c + 1];
            if (ce <= blk_e0 || cs >= blk_e1) continue;   // no edges of c here
            if (t < OC) {
                const float v = lacc[s * OC + t];
                if (cs >= blk_e0 && ce <= blk_e1) {
                    out[(size_t)c * OC + t] = v;          // interior: complete
                } else if (v != 0.f) {
                    atomicAdd(&out[(size_t)c * OC + t], v);  // boundary col
                }
            }
        }
    }
}

#define LDS_BYTES 59392

extern "C" void kernel_launch(void* const* d_in, const int* in_sizes, int n_in,
                              void* d_out, int out_size, void* d_ws, size_t ws_size,
                              hipStream_t stream) {
    const float* x    = (const float*)d_in[0];
    const int*   eidx = (const int*)d_in[1];
    const float* ea   = (const float*)d_in[2];
    const float* W1   = (const float*)d_in[3];
    const float* b1   = (const float*)d_in[4];
    const float* W2   = (const float*)d_in[5];
    const float* b2   = (const float*)d_in[6];
    float* out = (float*)d_out;

    const int E = in_sizes[1] / 2;

    char* ws = (char*)d_ws;
    float* xw1b      = (float*)ws;                        // 2 MB
    int*   hist8     = (int*)(ws + 2097152);              // 128 KB
    int*   cursor8   = (int*)(ws + 2097152 + 131072);     // 128 KB
    int*   colstart  = (int*)(ws + 2097152 + 262144);     // 16.4 KB
    int*   binloc    = (int*)(ws + 2097152 + 294912);     // 16 KB
    int*   blocksum  = (int*)(ws + 2097152 + 311296);     // 64 B
    int2*  csr       = (int2*)(ws + 2097152 + 327680);    // 2 MB
    float* dummy_out = (float*)(ws + 8388608);            // 2 MB scratch

    hipMemsetAsync(hist8, 0, 131072, stream);
    k_xw1<<<NN / 8, 128, 0, stream>>>(x, W1, b1, eidx, xw1b, out, hist8, E);
    k_scanA<<<16, 256, 0, stream>>>(hist8, binloc, blocksum);
    k_scanB<<<16, 256, 0, stream>>>(hist8, binloc, blocksum, cursor8, colstart, E);
    k_scatter<<<(E + 255) / 256, 256, 0, stream>>>(eidx, cursor8, csr, E);

    hipFuncSetAttribute(reinterpret_cast<const void*>(k_edge10),
                        hipFuncAttributeMaxDynamicSharedMemorySize, LDS_BYTES);
    // PROFILING PROBE: reps=10 into scratch (~810us > 650us poison fills ->
    // surfaces in rocprof top-5 WITH counters). Sacrifices this round's dur.
    k_edge10<<<NBLK, NT, LDS_BYTES, stream>>>(csr, ea, xw1b, W1, W2, b2,
                                              colstart, dummy_out, E, 10);
    // REAL dispatch (reps=1): byte-identical to round 17's kernel.
    k_edge10<<<NBLK, NT, LDS_BYTES, stream>>>(csr, ea, xw1b, W1, W2, b2,
                                              colstart, out, E, 1);
}

// Round 20
// 131.959 us; speedup vs baseline: 6.7599x; 6.7599x over previous
//
#include <hip/hip_runtime.h>
#include <hip/hip_bf16.h>

#define NN 4096
#define IC 128
#define OC 128
#define ED 16
#define EPB 64
#define NT 256
#define NSLOT 16
#define NBLK 512
#define NCPY 8

typedef __bf16 bf16x8 __attribute__((ext_vector_type(8)));
typedef float  f32x16 __attribute__((ext_vector_type(16)));

// raw barrier: drain LDS ops only; global loads/atomics stay in flight
#define BAR() do { asm volatile("s_waitcnt lgkmcnt(0)" ::: "memory"); \
    __builtin_amdgcn_s_barrier(); \
    __builtin_amdgcn_sched_barrier(0); } while (0)

__device__ __forceinline__ unsigned short bf16u(float f) {   // RNE f32->bf16
    unsigned int u = __float_as_uint(f);
    u = (u + 0x7FFFu + ((u >> 16) & 1u)) >> 16;
    return (unsigned short)u;
}
__device__ __forceinline__ float bf16tof(unsigned short h) {
    return __uint_as_float(((unsigned int)h) << 16);
}
__device__ __forceinline__ int swzk(int row) { return (row ^ (row >> 3)) & 7; }

// ---- Phase 1: xw1b = x@W1[:128]+b1; zero out; fused 8-replica hist ------
__global__ __launch_bounds__(128) void k_xw1(
    const float* __restrict__ x, const float* __restrict__ W1,
    const float* __restrict__ b1, const int* __restrict__ eidx,
    float* __restrict__ xw1b, float* __restrict__ out,
    int* __restrict__ hist8, int E)
{
    __shared__ float xs[8][IC];
    const int t = threadIdx.x;
    const int r0 = blockIdx.x * 8;
    #pragma unroll
    for (int r = 0; r < 8; ++r) xs[r][t] = x[(size_t)(r0 + r) * IC + t];

    const float4 z = make_float4(0.f, 0.f, 0.f, 0.f);
    float4* o4 = (float4*)out;
    o4[blockIdx.x * 256 + t]       = z;
    o4[blockIdx.x * 256 + 128 + t] = z;

    {   // fused hist; copy mapping matches k_scatter: edge e -> (e>>8)&7
        const int e0 = blockIdx.x * 512;
        #pragma unroll
        for (int j = 0; j < 4; ++j) {
            const int k = (2 * blockIdx.x + (j >> 1)) & (NCPY - 1);
            atomicAdd(&hist8[k * 4096 + eidx[E + e0 + t + j * 128]], 1);
        }
    }

    __syncthreads();
    float acc[8];
    const float bb = b1[t];
    #pragma unroll
    for (int r = 0; r < 8; ++r) acc[r] = bb;
    #pragma unroll 4
    for (int k = 0; k < IC; ++k) {
        const float w = W1[(size_t)k * OC + t];
        #pragma unroll
        for (int r = 0; r < 8; ++r) acc[r] = fmaf(xs[r][k], w, acc[r]);
    }
    #pragma unroll
    for (int r = 0; r < 8; ++r) xw1b[(size_t)(r0 + r) * OC + t] = acc[r];
}

// -------- scan (16-block A/B) + scatter (8-replica) -----------------------
__global__ __launch_bounds__(256) void k_scanA(
    const int* __restrict__ hist8, int* __restrict__ binloc,
    int* __restrict__ blocksum)
{
    __shared__ int sb[256];
    const int t = threadIdx.x;
    const int bin = blockIdx.x * 256 + t;
    int s = 0;
    #pragma unroll
    for (int k = 0; k < NCPY; ++k) s += hist8[k * 4096 + bin];
    sb[t] = s;
    __syncthreads();
    if (t == 0) {
        int a = 0;
        for (int i = 0; i < 256; ++i) { const int v = sb[i]; sb[i] = a; a += v; }
        blocksum[blockIdx.x] = a;
    }
    __syncthreads();
    binloc[bin] = sb[t];
}

__global__ __launch_bounds__(256) void k_scanB(
    const int* __restrict__ hist8, const int* __restrict__ binloc,
    const int* __restrict__ blocksum, int* __restrict__ cursor8,
    int* __restrict__ colstart, int E)
{
    __shared__ int baseL;
    const int t = threadIdx.x;
    if (t == 0) {
        int a = 0;
        for (int j = 0; j < (int)blockIdx.x; ++j) a += blocksum[j];
        baseL = a;
    }
    __syncthreads();
    const int bin = blockIdx.x * 256 + t;
    int off = baseL + binloc[bin];
    colstart[bin] = off;
    #pragma unroll
    for (int k = 0; k < NCPY; ++k) {
        cursor8[k * 4096 + bin] = off;
        off += hist8[k * 4096 + bin];
    }
    if (bin == 4095) colstart[4096] = E;
}

__global__ void k_scatter(const int* __restrict__ eidx, int* __restrict__ cursor8,
                          int2* __restrict__ csr, int E) {
    const int i = blockIdx.x * blockDim.x + threadIdx.x;
    const int k = blockIdx.x & (NCPY - 1);
    if (i < E) {
        const int row = eidx[i];
        const int col = eidx[E + i];
        const int pos = atomicAdd(&cursor8[k * 4096 + col], 1);
        csr[pos] = make_int2(row, col);
    }
}

// ---------------- Phase 2: BOTH layers on MFMA ----------------------------
// R19 counters (probe): VALUBusy 36%, MfmaUtil 13%, bank-conflict ~10% of
// cycles, BW 3%. Fix: layer-1 moves to mfma_32x32x16 with A = per-lane
// gathered ea (bf16 hi/lo; A-frag = 8 consecutive ea floats), B = w1-edge
// in registers (batch-invariant, like w2), C-init = xw1b gathered in
// D-layout (coalesced, L2-resident). Deletes 512 FMA/thread + ALL w1L/eaL
// LDS traffic (the 4-way-conflicted reads). h1 now written element-wise
// (b16 scatter, 2-way) from the MFMA D-layout. Layer-2/epilogue unchanged.
__global__ __launch_bounds__(NT, 2) void k_edge12(
    const int2* __restrict__ csr, const float* __restrict__ eattr,
    const float* __restrict__ xw1b, const float* __restrict__ W1,
    const float* __restrict__ W2, const float* __restrict__ b2,
    const int* __restrict__ colstart, float* __restrict__ out, int E)
{
    extern __shared__ char smem[];
    char*   const h1hi = smem;                      // 16KB bf16 [64e][128k] swz
    char*   const h1lo = smem + 16384;              // 16KB
    float*  const lacc = (float*)(smem + 32768);    // [16][128] (8KB)
    int*    const srowL = (int*)(smem + 40960);     // [4][64]
    int*    const scolL = srowL + 256;              // [4][64]

    const int t   = threadIdx.x;
    const int l   = t & 63;
    const int wid = t >> 6;                 // 4 waves
    const int lm  = l & 31;
    const int hi  = l >> 5;
    const int c2  = wid * 32 + lm;          // lane's output channel (both layers)

    // W2 -> register B-frags (batch-invariant, 64 VGPR)
    bf16x8 w2h[8], w2l[8];
    #pragma unroll
    for (int s = 0; s < 8; ++s) {
        union { unsigned short us[8]; bf16x8 v; } Uh, Ul;
        #pragma unroll
        for (int j = 0; j < 8; ++j) {
            const float w = W2[(size_t)(s * 16 + hi * 8 + j) * OC + c2];
            const unsigned short h = bf16u(w);
            Uh.us[j] = h;
            Ul.us[j] = bf16u(w - bf16tof(h));
        }
        w2h[s] = Uh.v; w2l[s] = Ul.v;
    }
    // W1 edge-part -> register B-frag (k = hi*8+j), hi/lo
    bf16x8 w1h, w1l;
    {
        union { unsigned short us[8]; bf16x8 v; } Uh, Ul;
        #pragma unroll
        for (int j = 0; j < 8; ++j) {
            const float w = W1[(size_t)(IC + hi * 8 + j) * OC + c2];
            const unsigned short h = bf16u(w);
            Uh.us[j] = h;
            Ul.us[j] = bf16u(w - bf16tof(h));
        }
        w1h = Uh.v; w1l = Ul.v;
    }
    const float b2s = b2[c2];

    #pragma unroll
    for (int i = 0; i < NSLOT * OC / NT; ++i) lacc[t + NT * i] = 0.f;

    const int nper = (E / EPB) / NBLK;      // 8 batches per block
    const int ibb  = blockIdx.x * nper;

    // ---- prologue: idx(0),idx(1) -> LDS bufs 0,1 ----
    if (t < EPB) {
        const int2 r0v = csr[(size_t)ibb * EPB + t];
        srowL[t] = r0v.x; scolL[t] = r0v.y;
        const int ib1 = (nper > 1) ? 1 : 0;
        const int2 r1v = csr[(size_t)(ibb + ib1) * EPB + t];
        srowL[64 + t] = r1v.x; scolL[64 + t] = r1v.y;
    }
    __syncthreads();
    const int colbase0 = scolL[0];          // block-fixed lacc anchor

    // ea(0) prefetch: lane owns edges lm (mt0) and 32+lm (mt1), k half hi*8..
    float4 pe0a, pe0b, pe1a, pe1b;
    {
        const int r0 = srowL[lm], cc0 = scolL[lm];
        const float* p0 = eattr + ((size_t)r0 * NN + cc0) * ED + hi * 8;
        pe0a = ((const float4*)p0)[0]; pe0b = ((const float4*)p0)[1];
        const int r1 = srowL[32 + lm], cc1 = scolL[32 + lm];
        const float* p1 = eattr + ((size_t)r1 * NN + cc1) * ED + hi * 8;
        pe1a = ((const float4*)p1)[0]; pe1b = ((const float4*)p1)[1];
    }
    int2 pidx;
    {
        const int ib2 = (nper > 2) ? 2 : (nper - 1);
        pidx = (t < EPB) ? csr[(size_t)(ibb + ib2) * EPB + t] : make_int2(0, 0);
    }

    for (int ii = 0; ii < nper; ++ii) {
        const int ib4 = ii & 3;             // idx buffer of batch ii

        // ======== Phase A: layer-1 MFMA -> h1 planes =====================
        // 1. ea -> bf16 hi/lo A-frags
        bf16x8 ah0, al0, ah1, al1;
        {
            const float f0[8] = { pe0a.x, pe0a.y, pe0a.z, pe0a.w,
                                  pe0b.x, pe0b.y, pe0b.z, pe0b.w };
            const float f1[8] = { pe1a.x, pe1a.y, pe1a.z, pe1a.w,
                                  pe1b.x, pe1b.y, pe1b.z, pe1b.w };
            union { unsigned short us[8]; bf16x8 v; } H0, L0, H1, L1;
            #pragma unroll
            for (int j = 0; j < 8; ++j) {
                unsigned short h = bf16u(f0[j]);
                H0.us[j] = h; L0.us[j] = bf16u(f0[j] - bf16tof(h));
                h = bf16u(f1[j]);
                H1.us[j] = h; L1.us[j] = bf16u(f1[j] - bf16tof(h));
            }
            ah0 = H0.v; al0 = L0.v; ah1 = H1.v; al1 = L1.v;
        }
        // 2. C-init: xw1b gathered in D-layout (row=(reg&3)+8*(reg>>2)+4hi)
        f32x16 acc0, acc1;
        #pragma unroll
        for (int reg = 0; reg < 16; ++reg) {
            const int r = (reg & 3) + 8 * (reg >> 2) + 4 * hi;
            acc0[reg] = xw1b[(size_t)srowL[ib4 * 64 + r] * OC + c2];
            acc1[reg] = xw1b[(size_t)srowL[ib4 * 64 + 32 + r] * OC + c2];
        }
        // 3. layer-1 MFMA: D = ea*W1e + xw1b (3-term bf16 split)
        acc0 = __builtin_amdgcn_mfma_f32_32x32x16_bf16(ah0, w1h, acc0, 0, 0, 0);
        acc1 = __builtin_amdgcn_mfma_f32_32x32x16_bf16(ah1, w1h, acc1, 0, 0, 0);
        acc0 = __builtin_amdgcn_mfma_f32_32x32x16_bf16(al0, w1h, acc0, 0, 0, 0);
        acc1 = __builtin_amdgcn_mfma_f32_32x32x16_bf16(al1, w1h, acc1, 0, 0, 0);
        acc0 = __builtin_amdgcn_mfma_f32_32x32x16_bf16(ah0, w1l, acc0, 0, 0, 0);
        acc1 = __builtin_amdgcn_mfma_f32_32x32x16_bf16(ah1, w1l, acc1, 0, 0, 0);
        // 4. relu + bf16 hi/lo split -> h1 planes (b16 scatter, D-layout)
        #pragma unroll
        for (int reg = 0; reg < 16; ++reg) {
            const int r = (reg & 3) + 8 * (reg >> 2) + 4 * hi;
            {
                const float f = fmaxf(acc0[reg], 0.f);
                const unsigned short h = bf16u(f);
                const unsigned short lo = bf16u(f - bf16tof(h));
                const int byt = r * 256 + ((c2 * 2) ^ (swzk(r) << 4));
                *(unsigned short*)(h1hi + byt) = h;
                *(unsigned short*)(h1lo + byt) = lo;
            }
            {
                const int r1 = r + 32;
                const float f = fmaxf(acc1[reg], 0.f);
                const unsigned short h = bf16u(f);
                const unsigned short lo = bf16u(f - bf16tof(h));
                const int byt = r1 * 256 + ((c2 * 2) ^ (swzk(r1) << 4));
                *(unsigned short*)(h1hi + byt) = h;
                *(unsigned short*)(h1lo + byt) = lo;
            }
        }
        // 5. idx(ii+2) -> LDS buf (ii+2)&3; load idx(ii+3)
        if (t < EPB) {
            srowL[((ii + 2) & 3) * 64 + t] = pidx.x;
            scolL[((ii + 2) & 3) * 64 + t] = pidx.y;
        }
        {
            const int iin = (ii + 3 < nper) ? (ii + 3) : (nper - 1);
            pidx = (t < EPB) ? csr[(size_t)(ibb + iin) * EPB + t] : make_int2(0, 0);
        }
        // 6. ea(ii+1) prefetch from idx buf (ii+1)&3
        {
            const int jb = (ii + 1) & 3;
            const int r0 = srowL[jb * 64 + lm], cc0 = scolL[jb * 64 + lm];
            const float* p0 = eattr + ((size_t)r0 * NN + cc0) * ED + hi * 8;
            pe0a = ((const float4*)p0)[0]; pe0b = ((const float4*)p0)[1];
            const int r1 = srowL[jb * 64 + 32 + lm], cc1 = scolL[jb * 64 + 32 + lm];
            const float* p1 = eattr + ((size_t)r1 * NN + cc1) * ED + hi * 8;
            pe1a = ((const float4*)p1)[0]; pe1b = ((const float4*)p1)[1];
        }
        BAR();  // h1 + idx(ii+2) visible; ea prefetch stays in flight

        // ======== Phase B: layer-2 MFMA + epilogue (unchanged) ==========
        {
            f32x16 La0 = (f32x16)(0.0f);
            f32x16 La1 = (f32x16)(0.0f);
            const int arow0 = lm;
            const int arow1 = 32 + lm;
            const int ak0 = swzk(arow0) << 4;
            const int ak1 = swzk(arow1) << 4;
            #pragma unroll
            for (int s = 0; s < 8; ++s) {
                const int kb = s * 32 + hi * 16;
                const bf16x8 aH0 = *(const bf16x8*)(h1hi + arow0 * 256 + (kb ^ ak0));
                const bf16x8 aL0 = *(const bf16x8*)(h1lo + arow0 * 256 + (kb ^ ak0));
                const bf16x8 aH1 = *(const bf16x8*)(h1hi + arow1 * 256 + (kb ^ ak1));
                const bf16x8 aL1 = *(const bf16x8*)(h1lo + arow1 * 256 + (kb ^ ak1));
                La0 = __builtin_amdgcn_mfma_f32_32x32x16_bf16(aH0, w2h[s], La0, 0, 0, 0);
                La1 = __builtin_amdgcn_mfma_f32_32x32x16_bf16(aH1, w2h[s], La1, 0, 0, 0);
                La0 = __builtin_amdgcn_mfma_f32_32x32x16_bf16(aL0, w2h[s], La0, 0, 0, 0);
                La1 = __builtin_amdgcn_mfma_f32_32x32x16_bf16(aL1, w2h[s], La1, 0, 0, 0);
                La0 = __builtin_amdgcn_mfma_f32_32x32x16_bf16(aH0, w2l[s], La0, 0, 0, 0);
                La1 = __builtin_amdgcn_mfma_f32_32x32x16_bf16(aH1, w2l[s], La1, 0, 0, 0);
            }

            // epilogue: run-combine into persistent lacc
            #pragma unroll
            for (int p = 0; p < 2; ++p) {
                const int mbase = p * 32 + 4 * hi;
                #pragma unroll
                for (int g = 0; g < 4; ++g) {
                    const int eb = mbase + 8 * g;
                    float sv;
                    {
                        const float a0 = (p == 0) ? La0[4 * g] : La1[4 * g];
                        sv = fmaxf(a0 + b2s, 0.f);
                    }
                    int ccur = scolL[ib4 * 64 + eb];
                    #pragma unroll
                    for (int j = 1; j < 4; ++j) {
                        const float aj = (p == 0) ? La0[4 * g + j] : La1[4 * g + j];
                        const float v = fmaxf(aj + b2s, 0.f);
                        const int c = scolL[ib4 * 64 + eb + j];
                        if (c == ccur) {
                            sv += v;
                        } else {
                            const int slot = ccur - colbase0;
                            if (slot < NSLOT) {
                                if (sv != 0.f) atomicAdd(&lacc[slot * OC + c2], sv);
                            } else {
                                if (sv != 0.f) atomicAdd(&out[(size_t)ccur * OC + c2], sv);
                            }
                            ccur = c; sv = v;
                        }
                    }
                    const int slot = ccur - colbase0;
                    if (slot < NSLOT) {
                        if (sv != 0.f) atomicAdd(&lacc[slot * OC + c2], sv);
                    } else {
                        if (sv != 0.f) atomicAdd(&out[(size_t)ccur * OC + c2], sv);
                    }
                }
            }
        }
        BAR();  // lacc(batch) complete; h1 reusable next phase A
    }

    // ---- single block-end flush (interior cols: plain store) -----------
    const int blk_e0 = ibb * EPB;
    const int blk_e1 = blk_e0 + nper * EPB;
    #pragma unroll 1
    for (int s = 0; s < NSLOT; ++s) {
        const int c = colbase0 + s;
        if (c >= NN) break;
        const int cs = colstart[c];
        const int ce = colstart[c + 1];
        if (ce <= blk_e0 || cs >= blk_e1) continue;
        if (t < OC) {
            const float v = lacc[s * OC + t];
            if (cs >= blk_e0 && ce <= blk_e1) {
                out[(size_t)c * OC + t] = v;
            } else if (v != 0.f) {
                atomicAdd(&out[(size_t)c * OC + t], v);
            }
        }
    }
}

#define LDS_BYTES 43008

extern "C" void kernel_launch(void* const* d_in, const int* in_sizes, int n_in,
                              void* d_out, int out_size, void* d_ws, size_t ws_size,
                              hipStream_t stream) {
    const float* x    = (const float*)d_in[0];
    const int*   eidx = (const int*)d_in[1];
    const float* ea   = (const float*)d_in[2];
    const float* W1   = (const float*)d_in[3];
    const float* b1   = (const float*)d_in[4];
    const float* W2   = (const float*)d_in[5];
    const float* b2   = (const float*)d_in[6];
    float* out = (float*)d_out;

    const int E = in_sizes[1] / 2;

    char* ws = (char*)d_ws;
    float* xw1b     = (float*)ws;                        // 2 MB
    int*   hist8    = (int*)(ws + 2097152);              // 128 KB
    int*   cursor8  = (int*)(ws + 2097152 + 131072);     // 128 KB
    int*   colstart = (int*)(ws + 2097152 + 262144);     // 16.4 KB
    int*   binloc   = (int*)(ws + 2097152 + 294912);     // 16 KB
    int*   blocksum = (int*)(ws + 2097152 + 311296);     // 64 B
    int2*  csr      = (int2*)(ws + 2097152 + 327680);    // 2 MB

    hipMemsetAsync(hist8, 0, 131072, stream);
    k_xw1<<<NN / 8, 128, 0, stream>>>(x, W1, b1, eidx, xw1b, out, hist8, E);
    k_scanA<<<16, 256, 0, stream>>>(hist8, binloc, blocksum);
    k_scanB<<<16, 256, 0, stream>>>(hist8, binloc, blocksum, cursor8, colstart, E);
    k_scatter<<<(E + 255) / 256, 256, 0, stream>>>(eidx, cursor8, csr, E);

    hipFuncSetAttribute(reinterpret_cast<const void*>(k_edge12),
                        hipFuncAttributeMaxDynamicSharedMemorySize, LDS_BYTES);
    k_edge12<<<NBLK, NT, LDS_BYTES, stream>>>(csr, ea, xw1b, W1, W2, b2,
                                              colstart, out, E);
}